// Round 15
// baseline (134.824 us; speedup 1.0000x reference)
//
#include <hip/hip_runtime.h>
#include <hip/hip_bf16.h>

// MPNNConv (R14 + layer1 single-wave-per-node full-row):
//   s[n] = h[n] @ W1[0:128] + b1 (f32 swz), g[n] = h[n] @ W1[128:256] (bf16 swz, L2-resident)
//   Hsum[n] = sum_{e: rows[e]=n} relu(s[n] + g[cols[e]] + ef[e] @ W1e)   (K=32 bf16 MFMA)
//   out[n]  = Hsum[n] @ W2 + deg[n]*b2
// CSR on-device; ef permuted into CSR order as bf16 (efb, 64B full-line records)
// + ccol. layer1: persistent 64-thread blocks, ONE wave owns a node's FULL
// 128-col row (8 MFMA/tile) -> efb/ccol stream read once per edge instead of
// twice (the 2-wave col-split duplicated it), and 2x per-tile work hides the
// g-gather latency. Full-row chunk mapping validated in R9's edge_kernel.
// counts zeroed by hipMemsetAsync BEFORE prep_hist (R11 cross-block race).

typedef __attribute__((ext_vector_type(8))) short bf16x8;
typedef __attribute__((ext_vector_type(4))) float f32x4;

#define ND 128
#define ED 32
#define NL1 4096   // persistent layer1 blocks (64 threads each)

__device__ __forceinline__ short f2bf(float x) {
  unsigned int u = __float_as_uint(x);
  unsigned int r = (u + 0x7FFFu + ((u >> 16) & 1u)) >> 16;
  return (short)r;
}

__device__ __forceinline__ float bf2f(short s) {
  return __uint_as_float(((unsigned int)(unsigned short)s) << 16);
}

__device__ __forceinline__ f32x4 bf8lo(bf16x8 v) {
  f32x4 r;
  #pragma unroll
  for (int j = 0; j < 4; ++j) r[j] = bf2f(v[j]);
  return r;
}
__device__ __forceinline__ f32x4 bf8hi(bf16x8 v) {
  f32x4 r;
  #pragma unroll
  for (int j = 0; j < 4; ++j) r[j] = bf2f(v[4 + j]);
  return r;
}

// swizzled offset within a 128-wide row for col c (c = ct*16 + cc)
__device__ __forceinline__ int swz(int c) {
  int ct = c >> 4, cc = c & 15;
  return (ct >> 2) * 64 + (cc >> 2) * 16 + (ct & 3) * 4 + (cc & 3);
}

// --- fused: weight pre-layouts (blocks [0,128)) | hist/rank/rc (rest) ---
__global__ __launch_bounds__(256) void prep_hist_kernel(
    const float* __restrict__ W1, const float* __restrict__ W2,
    const void* __restrict__ ei, int* __restrict__ counts,
    int* __restrict__ rank, unsigned int* __restrict__ rc,
    short* __restrict__ w12t, short* __restrict__ w1eA, short* __restrict__ w2t,
    int E) {
  int b = blockIdx.x;
  if (b < 128) {
    int t = b * 256 + threadIdx.x;
    if (t < 256 * 128) {  // w12t[n'][k]: n'<128 -> W1[k][n'] ; else W1[128+k][n'-128]
      int np = t >> 7, k = t & 127;
      float v = (np < 128) ? W1[k * 128 + np] : W1[(128 + k) * 128 + (np - 128)];
      w12t[t] = f2bf(v);
    }
    if (t < 128 * 128) {  // w2t[n][k] = W2[k][n]
      int n = t >> 7, k = t & 127;
      w2t[t] = f2bf(W2[k * 128 + n]);
    }
    if (t < 8 * 64 * 8) { // w1eA[ct][lane][j] = W1[256+lg*8+j][ct*16+li]
      int ct = t >> 9, lane = (t >> 3) & 63, j = t & 7;
      int li = lane & 15, lg = lane >> 4;
      w1eA[t] = f2bf(W1[(256 + lg * 8 + j) * 128 + ct * 16 + li]);
    }
  } else {
    int e = (b - 128) * 256 + threadIdx.x;
    if (e < E) {
      const unsigned int* u = (const unsigned int*)ei;
      int is64 = 1;
      #pragma unroll
      for (int i = 0; i < 16; ++i)
        if (u[2 * i + 1] != 0u) is64 = 0;   // uniform addresses -> scalar loads
      int r, c;
      if (is64) {
        r = (int)((const long long*)ei)[e];
        c = (int)((const long long*)ei)[(long long)E + e];
      } else {
        r = ((const int*)ei)[e];
        c = ((const int*)ei)[E + e];
      }
      rank[e] = atomicAdd(&counts[r], 1);
      rc[e] = ((unsigned int)r << 16) | (unsigned int)c;   // N < 65536
    }
  }
}

// --- single-block scan: 1024 threads x 16 elems ---
__global__ __launch_bounds__(1024) void scan_kernel(const int* __restrict__ counts,
                                                    int* __restrict__ row_ptr, int n) {
  __shared__ int wtot[16];
  int tid = threadIdx.x;
  int lane = tid & 63, w = tid >> 6;
  int base_i = tid * 16;
  int c[16];
  int tot = 0;
  #pragma unroll
  for (int j = 0; j < 16; ++j) {
    int i = base_i + j;
    c[j] = (i < n) ? counts[i] : 0;
    tot += c[j];
  }
  int x = tot;
  #pragma unroll
  for (int d = 1; d < 64; d <<= 1) {
    int t = __shfl_up(x, d);
    if (lane >= d) x += t;
  }
  if (lane == 63) wtot[w] = x;
  __syncthreads();
  if (w == 0) {
    int y = (lane < 16) ? wtot[lane] : 0;
    #pragma unroll
    for (int d = 1; d < 16; d <<= 1) {
      int t = __shfl_up(y, d);
      if (lane >= d) y += t;
    }
    if (lane < 16) wtot[lane] = y;
  }
  __syncthreads();
  int waveoff = (w == 0) ? 0 : wtot[w - 1];
  int run = waveoff + x - tot;  // exclusive prefix
  if (tid == 0) row_ptr[0] = 0;
  #pragma unroll
  for (int j = 0; j < 16; ++j) {
    int i = base_i + j;
    if (i < n) {
      run += c[j];
      row_ptr[i + 1] = run;
    }
  }
}

// --- fused: sg GEMM (blocks [0,SGB)) + ef->efb bf16 permute (rest) ---
__global__ __launch_bounds__(256, 4) void scatter_sg_kernel(
    const float* __restrict__ ef, const int* __restrict__ row_ptr,
    const int* __restrict__ rank, const unsigned int* __restrict__ rc,
    const float* __restrict__ h, const short* __restrict__ w12t,
    const float* __restrict__ b1, short* __restrict__ efb,
    int* __restrict__ ccol, float* __restrict__ s2, short* __restrict__ g2,
    int N, int E) {
  int b = blockIdx.x;
  int SGB = (N + 63) >> 6;
  if (b < SGB) {
    // ---- s = h@W1top + b1 (f32 swz), g = h@W1mid (bf16 swz)
    int lane = threadIdx.x & 63, w = threadIdx.x >> 6;
    int li = lane & 15, lg = lane >> 4;
    int base = b * 64 + w * 16;
    int rowm = base + li;
    if (rowm >= N) rowm = N - 1;
    float breg[8];
    #pragma unroll
    for (int nt = 0; nt < 8; ++nt) breg[nt] = b1[nt * 16 + li];
    f32x4 acc[16];
    #pragma unroll
    for (int nt = 0; nt < 16; ++nt) acc[nt] = (f32x4){0.f, 0.f, 0.f, 0.f};
    #pragma unroll
    for (int kc = 0; kc < 4; ++kc) {
      f32x4 f0 = *(const f32x4*)(h + (size_t)rowm * ND + kc * 32 + lg * 8);
      f32x4 f1 = *(const f32x4*)(h + (size_t)rowm * ND + kc * 32 + lg * 8 + 4);
      bf16x8 a;
      #pragma unroll
      for (int j = 0; j < 4; ++j) { a[j] = f2bf(f0[j]); a[4 + j] = f2bf(f1[j]); }
      #pragma unroll
      for (int nt = 0; nt < 16; ++nt) {
        bf16x8 bb = *(const bf16x8*)(w12t + (nt * 16 + li) * 128 + kc * 32 + lg * 8);
        acc[nt] = __builtin_amdgcn_mfma_f32_16x16x32_bf16(a, bb, acc[nt], 0, 0, 0);
      }
    }
    #pragma unroll
    for (int nt = 0; nt < 16; ++nt)
      #pragma unroll
      for (int r = 0; r < 4; ++r) {
        int row = base + lg * 4 + r;
        if (row < N) {
          if (nt < 8) {
            s2[(size_t)row * 128 + swz(nt * 16 + li)] = acc[nt][r] + breg[nt];
          } else {
            g2[(size_t)row * 128 + swz((nt - 8) * 16 + li)] = f2bf(acc[nt][r]);
          }
        }
      }
  } else {
    // ---- permute: 4 threads/edge; coalesced ef read, full-line scattered write
    int gt = (b - SGB) * 256 + threadIdx.x;
    int e = gt >> 2, part = gt & 3;
    if (e < E) {
      unsigned int p = rc[e];
      int r = (int)(p >> 16), c = (int)(p & 0xffffu);
      int pos = row_ptr[r] + rank[e];
      f32x4 a0 = *(const f32x4*)(ef + (size_t)e * ED + part * 8);
      f32x4 a1 = *(const f32x4*)(ef + (size_t)e * ED + part * 8 + 4);
      bf16x8 ob;
      #pragma unroll
      for (int j = 0; j < 4; ++j) { ob[j] = f2bf(a0[j]); ob[4 + j] = f2bf(a1[j]); }
      *(bf16x8*)(efb + (size_t)pos * ED + part * 8) = ob;
      if (part == 0) ccol[pos] = c;
    }
  }
}

// --- layer 1 + segment reduce: persistent 1-WAVE blocks, full 128-col row,
//     efb/ccol streamed ONCE per edge, g gathered from L2 (full row per edge) ---
__global__ __launch_bounds__(64) void layer1_kernel(
    const float* __restrict__ s2, const short* __restrict__ g2,
    const short* __restrict__ efb, const int* __restrict__ ccol,
    const short* __restrict__ w1eA, const int* __restrict__ row_ptr,
    float* __restrict__ hsum, int N) {
  int lane = threadIdx.x & 63;
  int li = lane & 15, lg = lane >> 4;

  // weights node-invariant: all 8 col-tiles resident for the block lifetime
  bf16x8 wa[8];
  #pragma unroll
  for (int ct = 0; ct < 8; ++ct)
    wa[ct] = *(const bf16x8*)(w1eA + (ct * 64 + lane) * 8);

  for (int node = blockIdx.x; node < N; node += NL1) {
    int rp = row_ptr[node], rpe = row_ptr[node + 1];
    int deg = rpe - rp;

    if (deg == 0) {
      if (li == 0) {
        #pragma unroll
        for (int ct = 0; ct < 8; ++ct)
          *(f32x4*)(hsum + (size_t)node * 128 + ct * 16 + lg * 4) =
              (f32x4){0.f, 0.f, 0.f, 0.f};
      }
      continue;
    }

    // sreg[ct] at swizzled offset (ct>>2)*64 + lg*16 + (ct&3)*4
    f32x4 sreg[8];
    #pragma unroll
    for (int ct = 0; ct < 8; ++ct)
      sreg[ct] = *(const f32x4*)(s2 + (size_t)node * 128 +
                                 (ct >> 2) * 64 + lg * 16 + (ct & 3) * 4);
    f32x4 psum[8];
    #pragma unroll
    for (int ct = 0; ct < 8; ++ct) psum[ct] = (f32x4){0.f, 0.f, 0.f, 0.f};

    int ntiles = (deg + 15) >> 4;
    int last = rpe - 1;
    auto ldpos = [&](int t) {
      int p = rp + t * 16 + li;
      return p > last ? last : p;
    };

    // prologue: tiles 0/1 staged; full g row (4x bf16x8) for tile 0 in flight
    int pA = ldpos(0), pB = ldpos(1);
    int cA = ccol[pA], cB = ccol[pB];
    bf16x8 eA = *(const bf16x8*)(efb + (size_t)pA * ED + lg * 8);
    bf16x8 eB = *(const bf16x8*)(efb + (size_t)pB * ED + lg * 8);
    const short* gpA = g2 + (size_t)cA * 128;
    bf16x8 gA0 = *(const bf16x8*)(gpA + lg * 16);
    bf16x8 gA1 = *(const bf16x8*)(gpA + lg * 16 + 8);
    bf16x8 gA2 = *(const bf16x8*)(gpA + 64 + lg * 16);
    bf16x8 gA3 = *(const bf16x8*)(gpA + 64 + lg * 16 + 8);

    for (int t = 0; t < ntiles; ++t) {
      // prefetch tile t+1's g row and tile t+2's pos/col/efb
      const short* gpB = g2 + (size_t)cB * 128;
      bf16x8 gB0 = *(const bf16x8*)(gpB + lg * 16);
      bf16x8 gB1 = *(const bf16x8*)(gpB + lg * 16 + 8);
      bf16x8 gB2 = *(const bf16x8*)(gpB + 64 + lg * 16);
      bf16x8 gB3 = *(const bf16x8*)(gpB + 64 + lg * 16 + 8);
      int pC = ldpos(t + 2);
      int cC = ccol[pC];
      bf16x8 eC = *(const bf16x8*)(efb + (size_t)pC * ED + lg * 8);
      // compute tile t: 8 MFMA covering all 128 output cols
      f32x4 acc[8];
      #pragma unroll
      for (int ct = 0; ct < 8; ++ct)
        acc[ct] = __builtin_amdgcn_mfma_f32_16x16x32_bf16(
            wa[ct], eA, (f32x4){0.f, 0.f, 0.f, 0.f}, 0, 0, 0);
      if ((t * 16 + li) < deg) {
        #pragma unroll
        for (int ct = 0; ct < 8; ++ct) {
          bf16x8 gr = (ct < 4) ? ((ct & 2) ? gA1 : gA0) : ((ct & 2) ? gA3 : gA2);
          f32x4 gv = (ct & 1) ? bf8hi(gr) : bf8lo(gr);
          f32x4 v = acc[ct] + sreg[ct] + gv;
          #pragma unroll
          for (int r = 0; r < 4; ++r)
            psum[ct][r] += (v[r] > 0.f ? v[r] : 0.f);
        }
      }
      // rotate
      cB = cC; eA = eB; eB = eC;
      gA0 = gB0; gA1 = gB1; gA2 = gB2; gA3 = gB3;
    }

    // reduce over the 16 li-lanes (edges), store full row from li==0
    #pragma unroll
    for (int ct = 0; ct < 8; ++ct)
      #pragma unroll
      for (int r = 0; r < 4; ++r) {
        float v = psum[ct][r];
        v += __shfl_xor(v, 1);
        v += __shfl_xor(v, 2);
        v += __shfl_xor(v, 4);
        v += __shfl_xor(v, 8);
        psum[ct][r] = v;
      }
    if (li == 0) {
      #pragma unroll
      for (int ct = 0; ct < 8; ++ct)
        *(f32x4*)(hsum + (size_t)node * 128 + ct * 16 + lg * 4) = psum[ct];
    }
  }
}

// --- out = Hsum @ W2 + deg*b2 ; 4 waves x 16 rows per block (MFMA) ---
__global__ __launch_bounds__(256) void out_kernel(const float* __restrict__ hsum,
                                                  const short* __restrict__ w2t,
                                                  const float* __restrict__ b2,
                                                  const int* __restrict__ row_ptr,
                                                  float* __restrict__ out, int N) {
  int lane = threadIdx.x & 63, w = threadIdx.x >> 6;
  int li = lane & 15, lg = lane >> 4;
  int base = blockIdx.x * 64 + w * 16;
  int rowm = base + li;
  if (rowm >= N) rowm = N - 1;
  float breg[8];
  #pragma unroll
  for (int nt = 0; nt < 8; ++nt) breg[nt] = b2[nt * 16 + li];
  f32x4 acc[8];
  #pragma unroll
  for (int nt = 0; nt < 8; ++nt) acc[nt] = (f32x4){0.f, 0.f, 0.f, 0.f};
  #pragma unroll
  for (int kc = 0; kc < 4; ++kc) {
    f32x4 f0 = *(const f32x4*)(hsum + (size_t)rowm * 128 + kc * 32 + lg * 8);
    f32x4 f1 = *(const f32x4*)(hsum + (size_t)rowm * 128 + kc * 32 + lg * 8 + 4);
    bf16x8 a;
    #pragma unroll
    for (int j = 0; j < 4; ++j) { a[j] = f2bf(f0[j]); a[4 + j] = f2bf(f1[j]); }
    #pragma unroll
    for (int nt = 0; nt < 8; ++nt) {
      bf16x8 bb = *(const bf16x8*)(w2t + (nt * 16 + li) * 128 + kc * 32 + lg * 8);
      acc[nt] = __builtin_amdgcn_mfma_f32_16x16x32_bf16(a, bb, acc[nt], 0, 0, 0);
    }
  }
  #pragma unroll
  for (int r = 0; r < 4; ++r) {
    int row = base + lg * 4 + r;
    if (row < N) {
      float dg = (float)(row_ptr[row + 1] - row_ptr[row]);
      #pragma unroll
      for (int nt = 0; nt < 8; ++nt)
        out[(size_t)row * 128 + nt * 16 + li] = acc[nt][r] + dg * breg[nt];
    }
  }
}

extern "C" void kernel_launch(void* const* d_in, const int* in_sizes, int n_in,
                              void* d_out, int out_size, void* d_ws, size_t ws_size,
                              hipStream_t stream) {
  const float* h  = (const float*)d_in[0];
  const void*  ei = d_in[1];
  const float* ef = (const float*)d_in[2];
  const float* W1 = (const float*)d_in[4];
  const float* b1 = (const float*)d_in[5];
  const float* W2 = (const float*)d_in[6];
  const float* b2 = (const float*)d_in[7];
  float* out = (float*)d_out;
  int N = in_sizes[0] / ND;
  int E = in_sizes[2] / ED;

  char* ws = (char*)d_ws;
  size_t off = 0;
  auto alloc = [&](size_t bytes) {
    size_t o = off;
    off = (off + bytes + 255) & ~(size_t)255;
    return o;
  };
  int*          counts  = (int*)(ws + alloc((size_t)N * 4));
  int*          row_ptr = (int*)(ws + alloc((size_t)(N + 1) * 4));
  int*          rank    = (int*)(ws + alloc((size_t)E * 4));
  unsigned int* rc      = (unsigned int*)(ws + alloc((size_t)E * 4));
  short*        w12t    = (short*)(ws + alloc(256 * 128 * 2));
  short*        w1eA    = (short*)(ws + alloc(8 * 64 * 8 * 2));
  short*        w2t     = (short*)(ws + alloc(128 * 128 * 2));
  float*        s2      = (float*)(ws + alloc((size_t)N * 128 * 4));
  short*        g2      = (short*)(ws + alloc((size_t)N * 128 * 2));
  float*        hsumb   = (float*)(ws + alloc((size_t)N * 128 * 4));
  short*        efb     = (short*)(ws + alloc((size_t)E * ED * 2));
  int*          ccol    = (int*)(ws + alloc((size_t)E * 4));

  int SGB = (N + 63) >> 6;
  int SCB = (4 * E + 255) >> 8;

  hipMemsetAsync(counts, 0, (size_t)N * 4, stream);   // MUST precede prep_hist (R11 race)
  prep_hist_kernel<<<128 + (E + 255) / 256, 256, 0, stream>>>(
      W1, W2, ei, counts, rank, rc, w12t, w1eA, w2t, E);
  scan_kernel<<<1, 1024, 0, stream>>>(counts, row_ptr, N);
  scatter_sg_kernel<<<SGB + SCB, 256, 0, stream>>>(
      ef, row_ptr, rank, rc, h, w12t, b1, efb, ccol, s2, g2, N, E);
  layer1_kernel<<<NL1, 64, 0, stream>>>(s2, g2, efb, ccol, w1eA, row_ptr, hsumb, N);
  out_kernel<<<(N + 63) / 64, 256, 0, stream>>>(hsumb, w2t, b2, row_ptr, out, N);
}